// Round 7
// baseline (293.246 us; speedup 1.0000x reference)
//
#include <hip/hip_runtime.h>
#include <math.h>

#define BN_EPS 1e-5
#define SIGMA 1.0f

// ============ conv1 partial: (8,128,64,64) -> fp32 partials, 3x3 s2 p1, fp64 acc ============
// grid 1024 = ocg(8) x isp(4: 32 ic) x b(8) x oht(4: 8 rows); block 256 = ow(32) x ohp(8)
__global__ __launch_bounds__(256, 4) void conv1_partial_kernel(
    const float* __restrict__ in, const float* __restrict__ w1,
    float* __restrict__ part)
{
    __shared__ double wlds[2304];   // [ic(32)][k(9)][j(8)] = 18.4 KB

    int bid = blockIdx.x;
    int oht = bid & 3;
    int b   = (bid >> 2) & 7;
    int isp = (bid >> 5) & 3;      // 32 ic per split
    int ocg = bid >> 7;            // high bits: input-sharing siblings share XCD slot pattern

    int tid = threadIdx.x;
    int ow  = tid & 31;
    int ohp = tid >> 5;            // 0..7
    int oh  = oht * 8 + ohp;
    int ih0 = 2 * oh - 1;
    int iw0 = 2 * ow - 1;

    for (int i = tid; i < 2304; i += 256) {
        int j  = i & 7;
        int t  = i >> 3;
        int k  = t % 9;
        int ic = t / 9;
        wlds[i] = (double)w1[((ocg * 8 + j) * 128 + isp * 32 + ic) * 9 + k];
    }
    __syncthreads();

    double acc[8];
    #pragma unroll
    for (int j = 0; j < 8; ++j) acc[j] = 0.0;

    bool rowok[3], colok[3];
    #pragma unroll
    for (int t = 0; t < 3; ++t) { rowok[t] = (ih0 + t) >= 0; colok[t] = (iw0 + t) >= 0; }

    const float* base0 = in + ((size_t)(b * 128 + isp * 32) * 64 + ih0) * 64 + iw0;

    float cur[9];
    #pragma unroll
    for (int t = 0; t < 3; ++t)
        #pragma unroll
        for (int kw = 0; kw < 3; ++kw)
            cur[t * 3 + kw] = (rowok[t] && colok[kw]) ? base0[t * 64 + kw] : 0.f;

    for (int ic = 0; ic < 32; ++ic) {
        float nxt[9];
        if (ic + 1 < 32) {
            const float* basen = base0 + (size_t)(ic + 1) * 4096;
            #pragma unroll
            for (int t = 0; t < 3; ++t)
                #pragma unroll
                for (int kw = 0; kw < 3; ++kw)
                    nxt[t * 3 + kw] = (rowok[t] && colok[kw]) ? basen[t * 64 + kw] : 0.f;
        }
        const double* wk = &wlds[ic * 72];
        #pragma unroll
        for (int k = 0; k < 9; ++k) {
            double x = (double)cur[k];
            double2 wa = *(const double2*)&wk[k * 8 + 0];
            double2 wb = *(const double2*)&wk[k * 8 + 2];
            double2 wc = *(const double2*)&wk[k * 8 + 4];
            double2 wd = *(const double2*)&wk[k * 8 + 6];
            acc[0] = fma(x, wa.x, acc[0]);
            acc[1] = fma(x, wa.y, acc[1]);
            acc[2] = fma(x, wb.x, acc[2]);
            acc[3] = fma(x, wb.y, acc[3]);
            acc[4] = fma(x, wc.x, acc[4]);
            acc[5] = fma(x, wc.y, acc[5]);
            acc[6] = fma(x, wd.x, acc[6]);
            acc[7] = fma(x, wd.y, acc[7]);
        }
        #pragma unroll
        for (int i = 0; i < 9; ++i) cur[i] = nxt[i];
    }

    #pragma unroll
    for (int j = 0; j < 8; ++j)
        part[isp * 524288 + ((b * 64 + ocg * 8 + j) * 32 + oh) * 32 + ow] = (float)acc[j];
}

// ============ conv1 combine: sum 4 partials + BN + ReLU -> y1 fp32 ============
__global__ __launch_bounds__(256) void conv1_combine_kernel(
    const float* __restrict__ part,
    const float* __restrict__ g, const float* __restrict__ be,
    const float* __restrict__ mn, const float* __restrict__ vr,
    float* __restrict__ y1)
{
    int idx = blockIdx.x * 256 + threadIdx.x;   // [b][oc][oh][ow], 524288 total
    int oc = (idx >> 10) & 63;
    double s = 0.0;
    #pragma unroll
    for (int p = 0; p < 4; ++p) s += (double)part[idx + p * 524288];
    double inv = (double)g[oc] / sqrt((double)vr[oc] + BN_EPS);
    double o = s * inv + ((double)be[oc] - (double)mn[oc] * inv);
    y1[idx] = fmaxf((float)o, 0.f);
}

// ============ conv2 FUSED: conv2(3x3 s2) + BN + ReLU + spatial mean -> ybar ============
// grid 64 = b(8) x ocg(8: 4 oc each); block 256 = 16x16 output spatial.
// Full 64-ic depth per block (8 LDS-staged chunks of 8 ic) -> complete per-element sum
// -> BN+ReLU in-register -> block reduce -> 4 ybar entries. part2 never materialized.
__global__ __launch_bounds__(256) void conv2_fused_kernel(
    const float* __restrict__ y1, const float* __restrict__ w2,
    const float* __restrict__ g, const float* __restrict__ be,
    const float* __restrict__ mn, const float* __restrict__ vr,
    double* __restrict__ ybar)
{
    __shared__ float  tin[8][33][34];   // 35.9 KB, one 8-ic chunk zero-padded
    __shared__ double wd[2304];         // [ic(64)][k(9)][j(4)] = 18.4 KB
    __shared__ double red[16];          // [wave(4)][j(4)]

    int bid = blockIdx.x;
    int ocg = bid & 7;                 // 4 oc per group
    int b   = bid >> 3;

    int tid = threadIdx.x;
    int ow  = tid & 15;
    int oh  = tid >> 4;

    // stage + convert all weights for this block's 4 oc
    for (int i = tid; i < 2304; i += 256) {
        int j  = i & 3;
        int t  = i >> 2;
        int k  = t % 9;
        int ic = t / 9;
        wd[i] = (double)w2[((ocg * 4 + j) * 64 + ic) * 9 + k];
    }

    double acc[4];
    #pragma unroll
    for (int j = 0; j < 4; ++j) acc[j] = 0.0;

    const float* inb = y1 + (size_t)b * 64 * 1024;

    for (int ch = 0; ch < 8; ++ch) {
        __syncthreads();               // prev chunk's compute done (and 1st: no-op)
        int ic0 = ch * 8;
        for (int lin = tid; lin < 8 * 33 * 34; lin += 256) {
            int c   = lin % 34;            // iw = c-1
            int t2  = lin / 34;
            int rr  = t2 % 33;             // ih = rr-1
            int icc = t2 / 1122 == 0 ? t2 / 33 : t2 / 33;  // icc = lin/1122
            icc = lin / 1122;
            int ih  = rr - 1;
            int iw  = c - 1;
            float v = 0.f;
            if ((unsigned)ih < 32u && (unsigned)iw < 32u)
                v = inb[((ic0 + icc) * 32 + ih) * 32 + iw];
            tin[icc][rr][c] = v;
        }
        __syncthreads();               // staging (and on ch=0, weights) visible

        for (int icc = 0; icc < 8; ++icc) {
            const double* wk = &wd[(ic0 + icc) * 36];
            #pragma unroll
            for (int kh = 0; kh < 3; ++kh) {
                #pragma unroll
                for (int kw = 0; kw < 3; ++kw) {
                    double x = (double)tin[icc][2 * oh + kh][2 * ow + kw];
                    const double* wj = &wk[(kh * 3 + kw) * 4];
                    double2 wa = *(const double2*)&wj[0];
                    double2 wb = *(const double2*)&wj[2];
                    acc[0] = fma(x, wa.x, acc[0]);
                    acc[1] = fma(x, wa.y, acc[1]);
                    acc[2] = fma(x, wb.x, acc[2]);
                    acc[3] = fma(x, wb.y, acc[3]);
                }
            }
        }
    }

    // BN + ReLU per element, then block spatial-reduce per oc
    double v[4];
    #pragma unroll
    for (int j = 0; j < 4; ++j) {
        int oc = ocg * 4 + j;
        double inv = (double)g[oc] / sqrt((double)vr[oc] + BN_EPS);
        double o = acc[j] * inv + ((double)be[oc] - (double)mn[oc] * inv);
        v[j] = fmax(o, 0.0);
    }
    #pragma unroll
    for (int off = 32; off > 0; off >>= 1)
        #pragma unroll
        for (int j = 0; j < 4; ++j) v[j] += __shfl_down(v[j], off, 64);
    __syncthreads();                   // reuse red[] safely
    if ((tid & 63) == 0) {
        int wv = tid >> 6;
        #pragma unroll
        for (int j = 0; j < 4; ++j) red[wv * 4 + j] = v[j];
    }
    __syncthreads();
    if (tid == 0) {
        #pragma unroll
        for (int j = 0; j < 4; ++j) {
            double s = red[j] + red[4 + j] + red[8 + j] + red[12 + j];
            ybar[b * 32 + ocg * 4 + j] = s * (1.0 / 256.0);
        }
    }
}

// ============ centers: conv3(1x1)+BN folded with the spatial mean, fp64 ============
__global__ __launch_bounds__(64) void centers_kernel(
    const double* __restrict__ ybar, const float* __restrict__ w3,
    const float* __restrict__ g, const float* __restrict__ be,
    const float* __restrict__ mn, const float* __restrict__ vr,
    double* __restrict__ cen_ws, float* __restrict__ cen_out)
{
    int t = threadIdx.x;
    if (t < 48) {
        int b = t / 6;
        int k = t % 6;
        double acc = 0.0;
        for (int ic = 0; ic < 32; ++ic) acc = fma((double)w3[k * 32 + ic], ybar[b * 32 + ic], acc);
        double inv = (double)g[k] / sqrt((double)vr[k] + BN_EPS);
        double c = acc * inv + ((double)be[k] - (double)mn[k] * inv);
        cen_ws[t]  = c;
        cen_out[t] = (float)c;
    }
}

// ============ quantization: fp64 dist/argmin, fp32 softmax; float4 I/O ============
__global__ __launch_bounds__(256) void quant_kernel(
    const float* __restrict__ x, const double* __restrict__ centers,
    float* __restrict__ qbar, float* __restrict__ qsoft,
    float* __restrict__ qhard, float* __restrict__ sym)
{
    int vid = blockIdx.x * 256 + threadIdx.x;   // float4 index; 2^17 vecs per batch
    int b = vid >> 17;

    double c[6];
    float cf[6];
    #pragma unroll
    for (int k = 0; k < 6; ++k) { c[k] = centers[b * 6 + k]; cf[k] = (float)c[k]; }

    float4 xv = ((const float4*)x)[vid];
    float xs[4] = {xv.x, xv.y, xv.z, xv.w};
    float r_bar[4], r_soft[4], r_hard[4], r_sym[4];

    #pragma unroll
    for (int i = 0; i < 4; ++i) {
        double xx = (double)xs[i];
        double d[6];
        double dmin = 1e300;
        int amin = 0;
        #pragma unroll
        for (int k = 0; k < 6; ++k) {
            double t = xx - c[k];
            d[k] = t * t;
            if (d[k] < dmin) { dmin = d[k]; amin = k; }
        }
        float se = 0.f, sw = 0.f;
        #pragma unroll
        for (int k = 0; k < 6; ++k) {
            float e = __expf(SIGMA * (float)(dmin - d[k]));
            se += e;
            sw += e * cf[k];
        }
        float qs = sw / se;
        float qh = cf[amin];
        r_soft[i] = qs;
        r_hard[i] = qh;
        r_bar[i]  = qh;
        r_sym[i]  = (float)amin;
    }

    ((float4*)qbar)[vid]  = make_float4(r_bar[0],  r_bar[1],  r_bar[2],  r_bar[3]);
    ((float4*)qsoft)[vid] = make_float4(r_soft[0], r_soft[1], r_soft[2], r_soft[3]);
    ((float4*)qhard)[vid] = make_float4(r_hard[0], r_hard[1], r_hard[2], r_hard[3]);
    ((float4*)sym)[vid]   = make_float4(r_sym[0],  r_sym[1],  r_sym[2],  r_sym[3]);
}

extern "C" void kernel_launch(void* const* d_in, const int* in_sizes, int n_in,
                              void* d_out, int out_size, void* d_ws, size_t ws_size,
                              hipStream_t stream) {
    const float* x  = (const float*)d_in[0];
    const float* cf = (const float*)d_in[1];
    const float* w1 = (const float*)d_in[2];
    const float* g1 = (const float*)d_in[3];
    const float* b1 = (const float*)d_in[4];
    const float* m1 = (const float*)d_in[5];
    const float* v1 = (const float*)d_in[6];
    const float* w2 = (const float*)d_in[7];
    const float* g2 = (const float*)d_in[8];
    const float* b2 = (const float*)d_in[9];
    const float* m2 = (const float*)d_in[10];
    const float* v2 = (const float*)d_in[11];
    const float* w3 = (const float*)d_in[12];
    const float* g3 = (const float*)d_in[13];
    const float* b3 = (const float*)d_in[14];
    const float* m3 = (const float*)d_in[15];
    const float* v3 = (const float*)d_in[16];

    const int NELEM = 8 * 128 * 64 * 64;      // 4,194,304
    float* out   = (float*)d_out;
    float* qbar  = out;
    float* qsoft = out + (size_t)NELEM;
    float* qhard = out + (size_t)2 * NELEM;
    float* sym   = out + (size_t)3 * NELEM;
    float* cen_o = out + (size_t)4 * NELEM;

    char* ws = (char*)d_ws;
    float*  part1 = (float*)(ws);                        // 4 x 524288 f32 = 8 MB
    float*  y1    = (float*)(ws + 8388608);              // 524288 f32 = 2 MB
    double* yb    = (double*)(ws + 10485760);            // 256 f64
    double* cen   = (double*)(ws + 10487808);            // 48 f64   (total ~10.5 MB)

    conv1_partial_kernel<<<1024, 256, 0, stream>>>(cf, w1, part1);
    conv1_combine_kernel<<<2048, 256, 0, stream>>>(part1, g1, b1, m1, v1, y1);
    conv2_fused_kernel<<<64, 256, 0, stream>>>(y1, w2, g2, b2, m2, v2, yb);
    centers_kernel<<<1, 64, 0, stream>>>(yb, w3, g3, b3, m3, v3, cen, cen_o);
    quant_kernel<<<NELEM / 4 / 256, 256, 0, stream>>>(x, cen, qbar, qsoft, qhard, sym);
}

// Round 8
// 180.736 us; speedup vs baseline: 1.6225x; 1.6225x over previous
//
#include <hip/hip_runtime.h>
#include <math.h>

#define BN_EPS 1e-5
#define SIGMA 1.0f

// ============ conv1 partial: (8,128,64,64) -> fp32 partials, 3x3 s2 p1, fp64 acc ============
// grid 1024 = ocg(8) x isp(8: 16 ic) x b(8) x oht(2: 16 rows); block 256 = ow(32) x ohp(8)
// thread: 2 output rows x 8 oc over 16 ic (144 FMA per 36 LDS-b128 -> 2x weight amortization)
__global__ __launch_bounds__(256, 4) void conv1_partial_kernel(
    const float* __restrict__ in, const float* __restrict__ w1,
    float* __restrict__ part)
{
    __shared__ double wlds[1152];   // [ic(16)][k(9)][j(8)] = 9.2 KB

    int bid = blockIdx.x;
    int oht = bid & 1;
    int b   = (bid >> 1) & 7;
    int isp = (bid >> 4) & 7;      // 16 ic per split
    int ocg = bid >> 7;            // high bits (stride 128): input-sharing siblings same XCD slot

    int tid = threadIdx.x;
    int ow  = tid & 31;
    int ohp = tid >> 5;            // 0..7
    int oh0 = oht * 16 + ohp * 2;  // rows oh0, oh0+1
    int ih0 = 2 * oh0 - 1;
    int iw0 = 2 * ow - 1;

    for (int i = tid; i < 1152; i += 256) {
        int j  = i & 7;
        int t  = i >> 3;
        int k  = t % 9;
        int ic = t / 9;
        wlds[i] = (double)w1[((ocg * 8 + j) * 128 + isp * 16 + ic) * 9 + k];
    }
    __syncthreads();

    double acc0[8], acc1[8];
    #pragma unroll
    for (int j = 0; j < 8; ++j) { acc0[j] = 0.0; acc1[j] = 0.0; }

    bool rowok[5], colok[3];
    #pragma unroll
    for (int t = 0; t < 5; ++t) rowok[t] = (ih0 + t) >= 0;
    #pragma unroll
    for (int t = 0; t < 3; ++t) colok[t] = (iw0 + t) >= 0;

    const float* base0 = in + ((size_t)(b * 128 + isp * 16) * 64 + ih0) * 64 + iw0;

    float cur[15];
    #pragma unroll
    for (int t = 0; t < 5; ++t)
        #pragma unroll
        for (int kw = 0; kw < 3; ++kw)
            cur[t * 3 + kw] = (rowok[t] && colok[kw]) ? base0[t * 64 + kw] : 0.f;

    for (int ic = 0; ic < 16; ++ic) {
        float nxt[15];
        if (ic + 1 < 16) {
            const float* basen = base0 + (size_t)(ic + 1) * 4096;
            #pragma unroll
            for (int t = 0; t < 5; ++t)
                #pragma unroll
                for (int kw = 0; kw < 3; ++kw)
                    nxt[t * 3 + kw] = (rowok[t] && colok[kw]) ? basen[t * 64 + kw] : 0.f;
        }
        double xv[15];
        #pragma unroll
        for (int i = 0; i < 15; ++i) xv[i] = (double)cur[i];

        const double* wk = &wlds[ic * 72];
        #pragma unroll
        for (int k = 0; k < 9; ++k) {
            int kh = k / 3, kw = k % 3;
            double2 wa = *(const double2*)&wk[k * 8 + 0];
            double2 wb = *(const double2*)&wk[k * 8 + 2];
            double2 wc = *(const double2*)&wk[k * 8 + 4];
            double2 wd = *(const double2*)&wk[k * 8 + 6];
            double x0 = xv[kh * 3 + kw];        // output row oh0
            double x1 = xv[(kh + 2) * 3 + kw];  // output row oh0+1
            acc0[0] = fma(x0, wa.x, acc0[0]);  acc1[0] = fma(x1, wa.x, acc1[0]);
            acc0[1] = fma(x0, wa.y, acc0[1]);  acc1[1] = fma(x1, wa.y, acc1[1]);
            acc0[2] = fma(x0, wb.x, acc0[2]);  acc1[2] = fma(x1, wb.x, acc1[2]);
            acc0[3] = fma(x0, wb.y, acc0[3]);  acc1[3] = fma(x1, wb.y, acc1[3]);
            acc0[4] = fma(x0, wc.x, acc0[4]);  acc1[4] = fma(x1, wc.x, acc1[4]);
            acc0[5] = fma(x0, wc.y, acc0[5]);  acc1[5] = fma(x1, wc.y, acc1[5]);
            acc0[6] = fma(x0, wd.x, acc0[6]);  acc1[6] = fma(x1, wd.x, acc1[6]);
            acc0[7] = fma(x0, wd.y, acc0[7]);  acc1[7] = fma(x1, wd.y, acc1[7]);
        }
        #pragma unroll
        for (int i = 0; i < 15; ++i) cur[i] = nxt[i];
    }

    #pragma unroll
    for (int j = 0; j < 8; ++j) {
        int idx0 = ((b * 64 + ocg * 8 + j) * 32 + oh0) * 32 + ow;
        part[isp * 524288 + idx0]      = (float)acc0[j];
        part[isp * 524288 + idx0 + 32] = (float)acc1[j];
    }
}

// ============ conv1 combine: sum 8 partials + BN + ReLU -> y1 fp32 ============
__global__ __launch_bounds__(256) void conv1_combine_kernel(
    const float* __restrict__ part,
    const float* __restrict__ g, const float* __restrict__ be,
    const float* __restrict__ mn, const float* __restrict__ vr,
    float* __restrict__ y1)
{
    int idx = blockIdx.x * 256 + threadIdx.x;   // [b][oc][oh][ow], 524288 total
    int oc = (idx >> 10) & 63;
    double s = 0.0;
    #pragma unroll
    for (int p = 0; p < 8; ++p) s += (double)part[idx + p * 524288];
    double inv = (double)g[oc] / sqrt((double)vr[oc] + BN_EPS);
    double o = s * inv + ((double)be[oc] - (double)mn[oc] * inv);
    y1[idx] = fmaxf((float)o, 0.f);
}

// ============ conv2 partial: (8,64,32,32) -> fp32 partials, 3x3 s2 p1 (r5-proven) ============
// grid 512 = isp(16: 4 ic) x b(8) x ocg(4); block 256 = full 16x16 spatial
__global__ __launch_bounds__(256) void conv2_partial_kernel(
    const float* __restrict__ y1, const float* __restrict__ w,
    float* __restrict__ part)
{
    __shared__ float tin[4][33][36];
    __shared__ float twt[4][9][8];

    int bid = blockIdx.x;
    int ocg = bid & 3;
    int b   = (bid >> 2) & 7;
    int isp = bid >> 5;

    int tid = threadIdx.x;
    int ow  = tid & 15;
    int oh  = tid >> 4;

    const float* inb = y1 + (size_t)(b * 64 + isp * 4) * 1024;

    for (int lin = tid; lin < 4 * 33 * 34; lin += 256) {
        int c   = lin % 34;
        int t2  = lin / 34;
        int rr  = t2 % 33;
        int icc = t2 / 33;
        int ih  = rr - 1;
        int iw  = c - 1;
        float v = 0.f;
        if ((unsigned)ih < 32u && (unsigned)iw < 32u)
            v = inb[(icc * 32 + ih) * 32 + iw];
        tin[icc][rr][c] = v;
    }
    for (int i = tid; i < 288; i += 256) {
        int j   = i & 7;
        int k   = (i >> 3) % 9;
        int icc = i / 72;
        twt[icc][k][j] = w[(ocg * 8 + j) * 576 + (isp * 4 + icc) * 9 + k];
    }
    __syncthreads();

    double acc[8];
    #pragma unroll
    for (int j = 0; j < 8; ++j) acc[j] = 0.0;

    for (int icc = 0; icc < 4; ++icc) {
        double xv[9];
        #pragma unroll
        for (int kh = 0; kh < 3; ++kh)
            #pragma unroll
            for (int kw = 0; kw < 3; ++kw)
                xv[kh * 3 + kw] = (double)tin[icc][2 * oh + kh][2 * ow + kw];
        #pragma unroll
        for (int k = 0; k < 9; ++k) {
            float4 wa = *(const float4*)&twt[icc][k][0];
            float4 wb = *(const float4*)&twt[icc][k][4];
            acc[0] = fma(xv[k], (double)wa.x, acc[0]);
            acc[1] = fma(xv[k], (double)wa.y, acc[1]);
            acc[2] = fma(xv[k], (double)wa.z, acc[2]);
            acc[3] = fma(xv[k], (double)wa.w, acc[3]);
            acc[4] = fma(xv[k], (double)wb.x, acc[4]);
            acc[5] = fma(xv[k], (double)wb.y, acc[5]);
            acc[6] = fma(xv[k], (double)wb.z, acc[6]);
            acc[7] = fma(xv[k], (double)wb.w, acc[7]);
        }
    }
    int obase = ((b * 32 + ocg * 8) * 16 + oh) * 16 + ow;
    #pragma unroll
    for (int j = 0; j < 8; ++j)
        part[isp * 65536 + obase + j * 256] = (float)acc[j];
}

// ============ conv2 combine + BN + ReLU + spatial mean -> ybar[256] (y2 never stored) ======
__global__ __launch_bounds__(256) void conv2_combine_ybar_kernel(
    const float* __restrict__ part,
    const float* __restrict__ g, const float* __restrict__ be,
    const float* __restrict__ mn, const float* __restrict__ vr,
    double* __restrict__ ybar)
{
    __shared__ double sm[4];
    int j  = blockIdx.x;             // j = b*32 + oc
    int oc = j & 31;
    int t  = threadIdx.x;
    int idx = j * 256 + t;
    double s = 0.0;
    #pragma unroll
    for (int p = 0; p < 16; ++p) s += (double)part[idx + p * 65536];
    double inv = (double)g[oc] / sqrt((double)vr[oc] + BN_EPS);
    double o = s * inv + ((double)be[oc] - (double)mn[oc] * inv);
    double v = fmax(o, 0.0);
    #pragma unroll
    for (int off = 32; off > 0; off >>= 1) v += __shfl_down(v, off, 64);
    if ((t & 63) == 0) sm[t >> 6] = v;
    __syncthreads();
    if (t == 0) ybar[j] = (sm[0] + sm[1] + sm[2] + sm[3]) * (1.0 / 256.0);
}

// ============ centers: conv3(1x1)+BN folded with the spatial mean, fp64 ============
__global__ __launch_bounds__(64) void centers_kernel(
    const double* __restrict__ ybar, const float* __restrict__ w3,
    const float* __restrict__ g, const float* __restrict__ be,
    const float* __restrict__ mn, const float* __restrict__ vr,
    double* __restrict__ cen_ws, float* __restrict__ cen_out)
{
    int t = threadIdx.x;
    if (t < 48) {
        int b = t / 6;
        int k = t % 6;
        double acc = 0.0;
        for (int ic = 0; ic < 32; ++ic) acc = fma((double)w3[k * 32 + ic], ybar[b * 32 + ic], acc);
        double inv = (double)g[k] / sqrt((double)vr[k] + BN_EPS);
        double c = acc * inv + ((double)be[k] - (double)mn[k] * inv);
        cen_ws[t]  = c;
        cen_out[t] = (float)c;
    }
}

// ============ quantization: fp64 dist/argmin, fp32 softmax; float4 I/O ============
__global__ __launch_bounds__(256) void quant_kernel(
    const float* __restrict__ x, const double* __restrict__ centers,
    float* __restrict__ qbar, float* __restrict__ qsoft,
    float* __restrict__ qhard, float* __restrict__ sym)
{
    int vid = blockIdx.x * 256 + threadIdx.x;   // float4 index; 2^17 vecs per batch
    int b = vid >> 17;

    double c[6];
    float cf[6];
    #pragma unroll
    for (int k = 0; k < 6; ++k) { c[k] = centers[b * 6 + k]; cf[k] = (float)c[k]; }

    float4 xv = ((const float4*)x)[vid];
    float xs[4] = {xv.x, xv.y, xv.z, xv.w};
    float r_bar[4], r_soft[4], r_hard[4], r_sym[4];

    #pragma unroll
    for (int i = 0; i < 4; ++i) {
        double xx = (double)xs[i];
        double d[6];
        double dmin = 1e300;
        int amin = 0;
        #pragma unroll
        for (int k = 0; k < 6; ++k) {
            double t = xx - c[k];
            d[k] = t * t;
            if (d[k] < dmin) { dmin = d[k]; amin = k; }
        }
        float se = 0.f, sw = 0.f;
        #pragma unroll
        for (int k = 0; k < 6; ++k) {
            float e = __expf(SIGMA * (float)(dmin - d[k]));
            se += e;
            sw += e * cf[k];
        }
        float qs = sw / se;
        float qh = cf[amin];
        r_soft[i] = qs;
        r_hard[i] = qh;
        r_bar[i]  = qh;
        r_sym[i]  = (float)amin;
    }

    ((float4*)qbar)[vid]  = make_float4(r_bar[0],  r_bar[1],  r_bar[2],  r_bar[3]);
    ((float4*)qsoft)[vid] = make_float4(r_soft[0], r_soft[1], r_soft[2], r_soft[3]);
    ((float4*)qhard)[vid] = make_float4(r_hard[0], r_hard[1], r_hard[2], r_hard[3]);
    ((float4*)sym)[vid]   = make_float4(r_sym[0],  r_sym[1],  r_sym[2],  r_sym[3]);
}

extern "C" void kernel_launch(void* const* d_in, const int* in_sizes, int n_in,
                              void* d_out, int out_size, void* d_ws, size_t ws_size,
                              hipStream_t stream) {
    const float* x  = (const float*)d_in[0];
    const float* cf = (const float*)d_in[1];
    const float* w1 = (const float*)d_in[2];
    const float* g1 = (const float*)d_in[3];
    const float* b1 = (const float*)d_in[4];
    const float* m1 = (const float*)d_in[5];
    const float* v1 = (const float*)d_in[6];
    const float* w2 = (const float*)d_in[7];
    const float* g2 = (const float*)d_in[8];
    const float* b2 = (const float*)d_in[9];
    const float* m2 = (const float*)d_in[10];
    const float* v2 = (const float*)d_in[11];
    const float* w3 = (const float*)d_in[12];
    const float* g3 = (const float*)d_in[13];
    const float* b3 = (const float*)d_in[14];
    const float* m3 = (const float*)d_in[15];
    const float* v3 = (const float*)d_in[16];

    const int NELEM = 8 * 128 * 64 * 64;      // 4,194,304
    float* out   = (float*)d_out;
    float* qbar  = out;
    float* qsoft = out + (size_t)NELEM;
    float* qhard = out + (size_t)2 * NELEM;
    float* sym   = out + (size_t)3 * NELEM;
    float* cen_o = out + (size_t)4 * NELEM;

    char* ws = (char*)d_ws;
    float*  part1 = (float*)(ws);                        // 8 x 524288 f32 = 16 MB
    float*  y1    = (float*)(ws + 16777216);             // 524288 f32 = 2 MB
    float*  part2 = (float*)(ws + 18874368);             // 16 x 65536 f32 = 4 MB
    double* yb    = (double*)(ws + 23068672);            // 256 f64
    double* cen   = (double*)(ws + 23070720);            // 48 f64   (total ~22 MB)

    conv1_partial_kernel<<<1024, 256, 0, stream>>>(cf, w1, part1);
    conv1_combine_kernel<<<2048, 256, 0, stream>>>(part1, g1, b1, m1, v1, y1);
    conv2_partial_kernel<<<512, 256, 0, stream>>>(y1, w2, part2);
    conv2_combine_ybar_kernel<<<256, 256, 0, stream>>>(part2, g2, b2, m2, v2, yb);
    centers_kernel<<<1, 64, 0, stream>>>(yb, w3, g3, b3, m3, v3, cen, cen_o);
    quant_kernel<<<NELEM / 4 / 256, 256, 0, stream>>>(x, cen, qbar, qsoft, qhard, sym);
}